// Round 5
// baseline (264.009 us; speedup 1.0000x reference)
//
#include <hip/hip_runtime.h>
#include <math.h>

#define EPSF 1e-9f
#define KK 128
#define MTOP 10   // m

// R12: instruction-count attack. Evidence: R10 (global GEMM) == R11
// (LDS-DMA GEMM) == 82us -> GEMM memory path exonerated. VALUBusy 45% =
// ~4x the essential FMA issue -> overhead ops (S broadcasts, addr math,
// k-combine shfls, divergence) + 50% occupancy are the cost.
//
// New decomposition: wave = 5 rows x all-128-k; lane owns 2 columns.
//  * S operands are wave-uniform -> readfirstlane-hoisted base -> scalar
//    loads into SGPRs (constant cache). Zero LDS S-reads, FMA reads the
//    SGPR operand directly (1 SGPR/VALU op is legal).
//  * P via DMA double-buffer (16-row chunks); inner read = 1 ds_read_b64
//    per k with compile-time offset. No k-combine, no identity divergence.
//  * Identity |S| values read once from global at the end (coalesced 8B).
//  * LDS = 2x8KB chunks only -> 16.4KB -> 8 blocks/CU (launch_bounds(256,8)).
//  * BIT-EXACTNESS: two accumulator sets accL (k 0..63) + accH (k 64..127),
//    added at the end = exactly the old half-split + combine rounding order.
//  * Bisection: verified lockstep + exact early-exit (count(>mid)==10 ->
//    m11 = masked butterfly-max of values <= mid). Ties fall through to
//    full convergence -> still exact.
// LESSONS kept: no runtime-indexed register arrays, macros not ref-helpers,
// small loop bodies (#pragma unroll 1 on chunk loops), 2*B workspace.

#define GLDS16(G, L) __builtin_amdgcn_global_load_lds(                    \
    (const __attribute__((address_space(1))) void*)(G),                   \
    (__attribute__((address_space(3))) void*)(L), 16, 0, 0)

// Wave w stages rows 4w..4w+3 of 16-row chunk T: 2 issues x 2 rows.
// Per-lane global source; wave-uniform LDS dest (HW adds lane*16).
#define STAGE(T, BUF)                                                     \
    { GLDS16(Pb + (size_t)((T) * 16 + 4 * wave + 0 + l5) * KK + (lx << 2),\
             &sP[BUF][(4 * wave + 0) * KK]);                              \
      GLDS16(Pb + (size_t)((T) * 16 + 4 * wave + 2 + l5) * KK + (lx << 2),\
             &sP[BUF][(4 * wave + 2) * KK]); }

// 8 k-values of chunk T, half H (0/1): p from LDS (b64, folded offsets),
// s from scalar loads (wave-uniform). Per-output k-ascending FMA order.
#define SUBCHUNK(BUFP, T, H, A0, A1)                                      \
    {                                                                     \
        const float* __restrict__ pb = (BUFP) + (H) * 8 * KK + j2;        \
        float2 p0 = *(const float2*)(pb + 0 * KK);                        \
        float2 p1 = *(const float2*)(pb + 1 * KK);                        \
        float2 p2 = *(const float2*)(pb + 2 * KK);                        \
        float2 p3 = *(const float2*)(pb + 3 * KK);                        \
        float2 p4 = *(const float2*)(pb + 4 * KK);                        \
        float2 p5 = *(const float2*)(pb + 5 * KK);                        \
        float2 p6 = *(const float2*)(pb + 6 * KK);                        \
        float2 p7 = *(const float2*)(pb + 7 * KK);                        \
        _Pragma("unroll")                                                 \
        for (int r = 0; r < 5; ++r) {                                     \
            const float* __restrict__ su = Su + r * KK + (T) * 16 + (H) * 8; \
            float4 sA = *(const float4*)(su);                             \
            float4 sB = *(const float4*)(su + 4);                         \
            A0[r] = fmaf(sA.x, p0.x, A0[r]); A1[r] = fmaf(sA.x, p0.y, A1[r]); \
            A0[r] = fmaf(sA.y, p1.x, A0[r]); A1[r] = fmaf(sA.y, p1.y, A1[r]); \
            A0[r] = fmaf(sA.z, p2.x, A0[r]); A1[r] = fmaf(sA.z, p2.y, A1[r]); \
            A0[r] = fmaf(sA.w, p3.x, A0[r]); A1[r] = fmaf(sA.w, p3.y, A1[r]); \
            A0[r] = fmaf(sB.x, p4.x, A0[r]); A1[r] = fmaf(sB.x, p4.y, A1[r]); \
            A0[r] = fmaf(sB.y, p5.x, A0[r]); A1[r] = fmaf(sB.y, p5.y, A1[r]); \
            A0[r] = fmaf(sB.z, p6.x, A0[r]); A1[r] = fmaf(sB.z, p6.y, A1[r]); \
            A0[r] = fmaf(sB.w, p7.x, A0[r]); A1[r] = fmaf(sB.w, p7.y, A1[r]); \
        }                                                                 \
    }

__global__ __launch_bounds__(256, 8) void fused_kernel(
    const float* __restrict__ y_pred, const float* __restrict__ y_true,
    const float* __restrict__ P, const float* __restrict__ samples,
    float* __restrict__ partial /* [2*B]: per-block {logmse_i, penalty_i} */)
{
    const int tid  = threadIdx.x;
    const int wave = tid >> 6;
    const int lane = tid & 63;
    const int b    = blockIdx.x;
    const int r0   = wave * 5;
    const int j2   = lane << 1;      // this lane's column pair (floats)
    const int l5   = lane >> 5;      // staging: row-within-issue
    const int lx   = lane & 31;      // staging: 16B slot within row

    const float* __restrict__ Pb = P + ((size_t)b << 14);            // b*128*128
    const float* __restrict__ Sb = samples + (size_t)b * (20 * KK);  // b*20*128
    // Wave-uniform S base: readfirstlane makes uniformity provable so the
    // compiler can select scalar (SMEM) loads for the GEMM operands.
    const int ru = __builtin_amdgcn_readfirstlane(r0);
    const float* __restrict__ Su = Sb + (size_t)ru * KK;

    __shared__ float sP[2][16 * KK]; // double-buffered 16-row P chunk (8KB ea)
    __shared__ float red[4];

    float accL0[5], accL1[5], accH0[5], accH1[5];
#pragma unroll
    for (int r = 0; r < 5; ++r) {
        accL0[r] = 0.f; accL1[r] = 0.f; accH0[r] = 0.f; accH1[r] = 0.f;
    }

    // ---- prologue: DMA chunk 0 ----
    STAGE(0, 0);
    __syncthreads();

    int cur = 0;
    // ---- chunks 0..3 (k 0..63) -> accL ----
#pragma unroll 1
    for (int t = 0; t < 4; ++t) {
        STAGE(t + 1, cur ^ 1);
        const float* __restrict__ bufp = &sP[0][0] + cur * (16 * KK);
        SUBCHUNK(bufp, t, 0, accL0, accL1)
        SUBCHUNK(bufp, t, 1, accL0, accL1)
        __syncthreads();
        cur ^= 1;
    }
    // ---- chunks 4..6 (k 64..111) -> accH, still prefetching ----
#pragma unroll 1
    for (int t = 4; t < 7; ++t) {
        STAGE(t + 1, cur ^ 1);
        const float* __restrict__ bufp = &sP[0][0] + cur * (16 * KK);
        SUBCHUNK(bufp, t, 0, accH0, accH1)
        SUBCHUNK(bufp, t, 1, accH0, accH1)
        __syncthreads();
        cur ^= 1;
    }
    // ---- epilogue chunk 7 ----
    {
        const float* __restrict__ bufp = &sP[0][0] + cur * (16 * KK);
        SUBCHUNK(bufp, 7, 0, accH0, accH1)
        SUBCHUNK(bufp, 7, 1, accH0, accH1)
    }

    // ---- magnitudes: 2 computed cols + 2 identity cols per lane ----
    // acc = accL + accH reproduces the verified half-split rounding order.
    float w0[5], w1[5], w2[5], w3[5];
#pragma unroll
    for (int r = 0; r < 5; ++r) {
        float2 sid = *(const float2*)(Sb + (size_t)(r0 + r) * KK + j2);
        w0[r] = fabsf(accL0[r] + accH0[r]);
        w1[r] = fabsf(accL1[r] + accH1[r]);
        w2[r] = fabsf(sid.x);
        w3[r] = fabsf(sid.y);
    }

    // ---- m1 per row: lane max + 6-shfl butterfly ----
    float mx[5];
#pragma unroll
    for (int r = 0; r < 5; ++r) {
        float lm = fmaxf(fmaxf(w0[r], w1[r]), fmaxf(w2[r], w3[r]));
#pragma unroll
        for (int d = 32; d >= 1; d >>= 1)
            lm = fmaxf(lm, __shfl_xor(lm, d, 64));
        mx[r] = lm;
    }

    // ---- m11 per row: lockstep ballot bisection + exact early-exit ----
    // count(>mid)==10  ->  m11 = max(values <= mid)  (masked butterfly).
    // Ties never produce count==10 -> fall through to full convergence.
    unsigned lo[5], hi[5];
    float m11v[5];
    int act[5];
#pragma unroll
    for (int r = 0; r < 5; ++r) {
        lo[r] = 0u; hi[r] = __float_as_uint(mx[r]); m11v[r] = 0.f; act[r] = 1;
    }

    while ((act[0] && lo[0] < hi[0]) || (act[1] && lo[1] < hi[1]) ||
           (act[2] && lo[2] < hi[2]) || (act[3] && lo[3] < hi[3]) ||
           (act[4] && lo[4] < hi[4])) {
#pragma unroll
        for (int r = 0; r < 5; ++r) {
            if (act[r] && lo[r] < hi[r]) {
                unsigned mid = lo[r] + ((hi[r] - lo[r] + 1u) >> 1);
                float mf = __uint_as_float(mid);
                int cnt = __popcll(__ballot(w0[r] > mf)) + __popcll(__ballot(w1[r] > mf))
                        + __popcll(__ballot(w2[r] > mf)) + __popcll(__ballot(w3[r] > mf));
                if (cnt == MTOP) {
                    float t0 = (w0[r] <= mf) ? w0[r] : 0.f;
                    float t1 = (w1[r] <= mf) ? w1[r] : 0.f;
                    float t2 = (w2[r] <= mf) ? w2[r] : 0.f;
                    float t3 = (w3[r] <= mf) ? w3[r] : 0.f;
                    float lm = fmaxf(fmaxf(t0, t1), fmaxf(t2, t3));
#pragma unroll
                    for (int d = 32; d >= 1; d >>= 1)
                        lm = fmaxf(lm, __shfl_xor(lm, d, 64));
                    m11v[r] = lm;
                    act[r] = 0;
                } else {
                    bool g = cnt >= (MTOP + 1);
                    lo[r] = g ? mid : lo[r];
                    hi[r] = g ? hi[r] : mid - 1u;
                }
            }
        }
    }

    float hmax = 0.f;
#pragma unroll
    for (int r = 0; r < 5; ++r) {
        float m11 = act[r] ? __uint_as_float(lo[r] + 1u) : m11v[r];
        hmax = fmaxf(hmax, mx[r] / (m11 + EPSF));  // wave-uniform
    }

    // ---- combine 4 waves; per-block partials (no atomics) ----
    if (lane == 0) red[wave] = hmax;
    __syncthreads();
    if (tid == 0) {
        float hb  = fmaxf(fmaxf(red[0], red[1]), fmaxf(red[2], red[3]));
        float ypv = y_pred[b];
        float yp  = fmaxf(ypv, EPSF);
        float yt  = fmaxf(y_true[b], EPSF);
        float d   = log2f(yt) - log2f(yp);
        partial[2 * b]     = d * d;
        partial[2 * b + 1] = fmaxf(hb - ypv, 0.f);
    }
}

__global__ __launch_bounds__(256) void finalize_kernel(
    const float* __restrict__ partial, float* __restrict__ out, float invB)
{
    const int t = threadIdx.x;
    float sl = 0.f, sp = 0.f;
#pragma unroll
    for (int i = 0; i < 8; ++i) {
        float2 v = *(const float2*)(partial + 2 * (t + i * 256));
        sl += v.x; sp += v.y;
    }
#pragma unroll
    for (int d = 32; d >= 1; d >>= 1) {
        sl += __shfl_xor(sl, d, 64);
        sp += __shfl_xor(sp, d, 64);
    }
    __shared__ float rl[4], rp[4];
    const int w = t >> 6;
    if ((t & 63) == 0) { rl[w] = sl; rp[w] = sp; }
    __syncthreads();
    if (t == 0) {
        float L = (rl[0] + rl[1] + rl[2] + rl[3]) * invB;
        float V = (rp[0] + rp[1] + rp[2] + rp[3]) * invB;
        out[0] = L + 0.5f * V;
        out[1] = L;
        out[2] = V;
    }
}

extern "C" void kernel_launch(void* const* d_in, const int* in_sizes, int n_in,
                              void* d_out, int out_size, void* d_ws, size_t ws_size,
                              hipStream_t stream) {
    const float* y_pred  = (const float*)d_in[0];
    const float* y_true  = (const float*)d_in[1];
    const float* P       = (const float*)d_in[2];
    const float* samples = (const float*)d_in[3];
    const int B = in_sizes[0];           // y_pred has B elements

    float* partial = (float*)d_ws;       // 2*B floats, fully overwritten

    fused_kernel<<<B, 256, 0, stream>>>(y_pred, y_true, P, samples, partial);
    finalize_kernel<<<1, 256, 0, stream>>>(partial, (float*)d_out, 1.0f / (float)B);
}

// Round 7
// 243.858 us; speedup vs baseline: 1.0826x; 1.0826x over previous
//
#include <hip/hip_runtime.h>
#include <math.h>

#define EPSF 1e-9f
#define KK 128
#define MTOP 10   // m

// R14 = R13 with the staging-coverage bug fixed. R13 staged only 64 of 128
// P rows (4 waves x 8 issues x 2 rows) -> upper k-half read garbage -> inf.
// Now: 16 issues/wave, wave w stages rows 32w..32w+31. Theory unchanged:
//
// De-convoy the fetch. Evidence R7/R10/R11 (three load structures) all
// = 82-87us, hbm_gbps pinned ~930, FETCH ~76MB -> per-CU fetch-capacity
// limit, convoyed by per-chunk vmcnt(0) barriers. Stage the WHOLE 64KB P
// panel in one DMA burst (16 global_load_lds per wave, 128KB+ outstanding
// per CU), ONE barrier, then the verified GEMM+selection runs barrier-free
// from LDS.
//  * LDS 74KB -> 2 blocks/CU (25% occupancy) ON PURPOSE: discriminates
//    fetch-capacity-bound (predicts win) vs occupancy-bound (twice falsified).
//  * launch_bounds(256,2) -> VGPR cap 256: no R12-style spill (R12: cap 64,
//    alloc 32, WRITE_SIZE 6.2MB of scratch).
//  * Math bit-identical to verified R7/R11: k-split half-waves, float4 P
//    reads (ds_read_b128 from sP), shfl k-combine + identity trick,
//    butterfly m1, pure lockstep ballot bisection, per-block partials.
// LESSONS: compile-time register-array indices; no full GEMM unroll; never
// starve the VGPR cap; workspace stays 2*B floats; no global atomics;
// VERIFY staging covers every row (R13!).

#define GLDS16(G, L) __builtin_amdgcn_global_load_lds(                    \
    (const __attribute__((address_space(1))) void*)(G),                   \
    (__attribute__((address_space(3))) void*)(L), 16, 0, 0)

__global__ __launch_bounds__(256, 2) void fused_kernel(
    const float* __restrict__ y_pred, const float* __restrict__ y_true,
    const float* __restrict__ P, const float* __restrict__ samples,
    float* __restrict__ partial /* [2*B]: per-block {logmse_i, penalty_i} */)
{
    const int tid   = threadIdx.x;
    const int wave  = tid >> 6;
    const int lane  = tid & 63;
    const int b     = blockIdx.x;
    const int r0    = wave * 5;
    const int sg    = lane >> 5;     // k-segment of the half-wave
    const int c     = lane & 31;     // column group
    const int j4    = c << 2;
    const int kbase = sg << 6;       // 0 or 64
    const int l5    = lane >> 5;     // staging: row-within-issue
    const int lx    = lane & 31;     // staging: 16B slot within row

    const float* __restrict__ Pb = P + ((size_t)b << 14);            // b*128*128
    const float* __restrict__ Sb = samples + (size_t)b * (20 * KK);  // b*20*128

    __shared__ float sP[128 * KK];  // FULL P panel, 64KB
    __shared__ float sS[20 * KK];   // S rows: broadcast + identity values
    __shared__ float red[4];

    // ---- burst-stage the full P panel: wave w rows 32w..32w+31, 16 DMAs ----
    // Each issue: 2 rows x 512B. Per-lane global src; wave-uniform LDS dest
    // (HW adds lane*16). 16 issues x 2 rows x 4 waves = all 128 rows.
#pragma unroll
    for (int i = 0; i < 16; ++i) {
        GLDS16(Pb + (size_t)(32 * wave + 2 * i + l5) * KK + (lx << 2),
               &sP[(32 * wave + 2 * i) * KK]);
    }

    // ---- stage S into LDS, block-cooperative, coalesced float2 ----
#pragma unroll
    for (int i = 0; i < 5; ++i) {
        const int idx = (i * 256 + tid) * 2;
        *(float2*)&sS[idx] = *(const float2*)(Sb + idx);
    }

    float4 acc[5];
#pragma unroll
    for (int r = 0; r < 5; ++r) acc[r] = make_float4(0.f, 0.f, 0.f, 0.f);

    // ---- ONE barrier: drains all waves' DMAs (vmcnt0) + sS writes ----
    __syncthreads();

    // ---- GEMM over this half-wave's 64 k values, all from LDS ----
#pragma unroll 2
    for (int kk = 0; kk < 64; kk += 4) {
        const float* __restrict__ pb = &sP[(kbase + kk) * KK + j4];
        float4 p0 = *(const float4*)(pb + 0 * KK);
        float4 p1 = *(const float4*)(pb + 1 * KK);
        float4 p2 = *(const float4*)(pb + 2 * KK);
        float4 p3 = *(const float4*)(pb + 3 * KK);
#pragma unroll
        for (int r = 0; r < 5; ++r) {
            float4 s = *(const float4*)&sS[(r0 + r) * KK + kbase + kk];
            acc[r].x = fmaf(s.x, p0.x, acc[r].x);
            acc[r].y = fmaf(s.x, p0.y, acc[r].y);
            acc[r].z = fmaf(s.x, p0.z, acc[r].z);
            acc[r].w = fmaf(s.x, p0.w, acc[r].w);
            acc[r].x = fmaf(s.y, p1.x, acc[r].x);
            acc[r].y = fmaf(s.y, p1.y, acc[r].y);
            acc[r].z = fmaf(s.y, p1.z, acc[r].z);
            acc[r].w = fmaf(s.y, p1.w, acc[r].w);
            acc[r].x = fmaf(s.z, p2.x, acc[r].x);
            acc[r].y = fmaf(s.z, p2.y, acc[r].y);
            acc[r].z = fmaf(s.z, p2.z, acc[r].z);
            acc[r].w = fmaf(s.z, p2.w, acc[r].w);
            acc[r].x = fmaf(s.w, p3.x, acc[r].x);
            acc[r].y = fmaf(s.w, p3.y, acc[r].y);
            acc[r].z = fmaf(s.w, p3.z, acc[r].z);
            acc[r].w = fmaf(s.w, p3.w, acc[r].w);
        }
    }

    // ---- combine k-halves; upper half-wave switches to identity values ----
    float w0[5], w1[5], w2[5], w3[5];
#pragma unroll
    for (int r = 0; r < 5; ++r) {
        float ax = acc[r].x + __shfl_xor(acc[r].x, 32, 64);
        float ay = acc[r].y + __shfl_xor(acc[r].y, 32, 64);
        float az = acc[r].z + __shfl_xor(acc[r].z, 32, 64);
        float aw = acc[r].w + __shfl_xor(acc[r].w, 32, 64);
        float4 idv = *(const float4*)&sS[(r0 + r) * KK + j4];
        w0[r] = fabsf(sg ? idv.x : ax);
        w1[r] = fabsf(sg ? idv.y : ay);
        w2[r] = fabsf(sg ? idv.z : az);
        w3[r] = fabsf(sg ? idv.w : aw);
    }

    // ---- m1 per row: lane max + 6-shfl butterfly (5 chains interleave) ----
    float mx[5];
#pragma unroll
    for (int r = 0; r < 5; ++r) {
        float lm = fmaxf(fmaxf(w0[r], w1[r]), fmaxf(w2[r], w3[r]));
#pragma unroll
        for (int d = 32; d >= 1; d >>= 1)
            lm = fmaxf(lm, __shfl_xor(lm, d, 64));
        mx[r] = lm;
    }

    // ---- m11 per row: LOCKSTEP ballot bisection on float bit patterns ----
    // Invariant per row: pattern(m11) in [lo+1, hi+1]; converged rows take
    // the lo=mid branch forever (stable no-op), so lockstep is safe.
    unsigned lo[5], hi[5];
#pragma unroll
    for (int r = 0; r < 5; ++r) { lo[r] = 0u; hi[r] = __float_as_uint(mx[r]); }

    while (lo[0] < hi[0] || lo[1] < hi[1] || lo[2] < hi[2] ||
           lo[3] < hi[3] || lo[4] < hi[4]) {
#pragma unroll
        for (int r = 0; r < 5; ++r) {
            unsigned mid = lo[r] + ((hi[r] - lo[r] + 1u) >> 1);
            float mf = __uint_as_float(mid);
            int cnt = __popcll(__ballot(w0[r] > mf)) + __popcll(__ballot(w1[r] > mf))
                    + __popcll(__ballot(w2[r] > mf)) + __popcll(__ballot(w3[r] > mf));
            bool g = cnt >= (MTOP + 1);
            lo[r] = g ? mid : lo[r];
            hi[r] = g ? hi[r] : mid - 1u;
        }
    }

    float hmax = 0.f;
#pragma unroll
    for (int r = 0; r < 5; ++r) {
        float m11 = __uint_as_float(lo[r] + 1u);   // exact 11th-largest
        hmax = fmaxf(hmax, mx[r] / (m11 + EPSF));  // wave-uniform
    }

    // ---- combine 4 waves; per-block partials (no atomics) ----
    if (lane == 0) red[wave] = hmax;
    __syncthreads();
    if (tid == 0) {
        float hb  = fmaxf(fmaxf(red[0], red[1]), fmaxf(red[2], red[3]));
        float ypv = y_pred[b];
        float yp  = fmaxf(ypv, EPSF);
        float yt  = fmaxf(y_true[b], EPSF);
        float d   = log2f(yt) - log2f(yp);
        partial[2 * b]     = d * d;
        partial[2 * b + 1] = fmaxf(hb - ypv, 0.f);
    }
}

__global__ __launch_bounds__(256) void finalize_kernel(
    const float* __restrict__ partial, float* __restrict__ out, float invB)
{
    const int t = threadIdx.x;
    float sl = 0.f, sp = 0.f;
#pragma unroll
    for (int i = 0; i < 8; ++i) {
        float2 v = *(const float2*)(partial + 2 * (t + i * 256));
        sl += v.x; sp += v.y;
    }
#pragma unroll
    for (int d = 32; d >= 1; d >>= 1) {
        sl += __shfl_xor(sl, d, 64);
        sp += __shfl_xor(sp, d, 64);
    }
    __shared__ float rl[4], rp[4];
    const int w = t >> 6;
    if ((t & 63) == 0) { rl[w] = sl; rp[w] = sp; }
    __syncthreads();
    if (t == 0) {
        float L = (rl[0] + rl[1] + rl[2] + rl[3]) * invB;
        float V = (rp[0] + rp[1] + rp[2] + rp[3]) * invB;
        out[0] = L + 0.5f * V;
        out[1] = L;
        out[2] = V;
    }
}

extern "C" void kernel_launch(void* const* d_in, const int* in_sizes, int n_in,
                              void* d_out, int out_size, void* d_ws, size_t ws_size,
                              hipStream_t stream) {
    const float* y_pred  = (const float*)d_in[0];
    const float* y_true  = (const float*)d_in[1];
    const float* P       = (const float*)d_in[2];
    const float* samples = (const float*)d_in[3];
    const int B = in_sizes[0];           // y_pred has B elements

    float* partial = (float*)d_ws;       // 2*B floats, fully overwritten

    fused_kernel<<<B, 256, 0, stream>>>(y_pred, y_true, P, samples, partial);
    finalize_kernel<<<1, 256, 0, stream>>>(partial, (float*)d_out, 1.0f / (float)B);
}

// Round 8
// 234.889 us; speedup vs baseline: 1.1240x; 1.0382x over previous
//
#include <hip/hip_runtime.h>
#include <math.h>

#define EPSF 1e-9f
#define KK 128
#define MTOP 10   // m

// R15: sustain memory-level parallelism. Evidence: R7/R10/R11 all 82-87us,
// R14 (one-shot 128KB burst, 2 blk/CU) 94.6us; delivered BW stuck at
// 1.84 TB/s aggregate = 7.2 GB/s/CU ~= 30% of streaming ceiling. Cause:
// every prior structure drains vmcnt to 0 (load-use waits or __syncthreads'
// implicit vmcnt(0)) -> sawtooth, ~5KB avg outstanding/CU (Little's law
// matches 1.84 TB/s at ~800ns). Fix = T3/T4-minimum: counted vmcnt + raw
// s_barrier, NEVER draining in the main loop.
//  * P in 16 chunks x 8 rows (4 rows from each k-half -> both half-waves
//    always busy). 5-buffer LDS ring (chunk t -> buf t%5): writer t+4 never
//    collides with readers t..t+3 (distinct mod 5).
//  * Prefetch depth 4: 16KB in flight per block SUSTAINED, x4-5 blocks/CU.
//  * Per chunk: wave w DMAs 2 rows (1 global_load_lds, wave-uniform LDS
//    dest, linear); waits s_waitcnt vmcnt(3) (own chunk arrived, 3 newer
//    still flying); raw s_barrier (all waves' parts visible); compute.
//  * Tail t=12..15: literal vmcnt 3/2/1/0 (macro, straight-line).
//  * sched_barrier(0) around waits+barriers (rule: hipcc hoists past asm
//    waitcnt); explicit lgkmcnt(0) before first barrier for sS ds_writes.
//  * Math bit-identical to verified R7/R11: k-ascending FMA order per half,
//    shfl k-combine + identity trick, butterfly m1, lockstep bisection.
// LESSONS: coverage check 16x8=128 rows ALL staged (R13!); no full-drain
// __syncthreads inside pipeline; VGPR cap via launch_bounds(256,4)=128 (no
// R12 spill); workspace 2*B floats; compile-time register-array indices.

#define GLDS16(G, L) __builtin_amdgcn_global_load_lds(                    \
    (const __attribute__((address_space(1))) void*)(G),                   \
    (__attribute__((address_space(3))) void*)(L), 16, 0, 0)

// Chunk T rows: {4T..4T+3} (k-half 0) + {64+4T..64+4T+3} (k-half 1).
// Wave w stages 2 rows: global row 4T + 2*(w&1) + 64*(w>>1) + l5,
// LDS local row 2*(w&1) + 4*(w>>1). All 4 waves x 2 rows = 8 rows/chunk.
#define STAGE(T, BUF)                                                     \
    GLDS16(Pb + (size_t)(((T) << 2) + ((wave & 1) << 1) +                 \
                         ((wave >> 1) << 6) + l5) * KK + (lx << 2),       \
           &sP[(BUF) * (8 * KK) + (((wave & 1) << 1) +                    \
                                   ((wave >> 1) << 2)) * KK])

// Compute chunk T from ring buffer BUF: this half-wave's 4 k-values.
// Local P rows sg*4..sg*4+3 <-> global k kbase+4T..+3. k-ascending order.
#define COMPUTE(T, BUF)                                                   \
    {                                                                     \
        const float* __restrict__ pb =                                    \
            &sP[(BUF) * (8 * KK) + (sg << 2) * KK + j4];                  \
        float4 p0 = *(const float4*)(pb + 0 * KK);                        \
        float4 p1 = *(const float4*)(pb + 1 * KK);                        \
        float4 p2 = *(const float4*)(pb + 2 * KK);                        \
        float4 p3 = *(const float4*)(pb + 3 * KK);                        \
        const int kk = (T) << 2;                                          \
        _Pragma("unroll")                                                 \
        for (int r = 0; r < 5; ++r) {                                     \
            float4 s = *(const float4*)&sS[(r0 + r) * KK + kbase + kk];   \
            acc[r].x = fmaf(s.x, p0.x, acc[r].x);                         \
            acc[r].y = fmaf(s.x, p0.y, acc[r].y);                         \
            acc[r].z = fmaf(s.x, p0.z, acc[r].z);                         \
            acc[r].w = fmaf(s.x, p0.w, acc[r].w);                         \
            acc[r].x = fmaf(s.y, p1.x, acc[r].x);                         \
            acc[r].y = fmaf(s.y, p1.y, acc[r].y);                         \
            acc[r].z = fmaf(s.y, p1.z, acc[r].z);                         \
            acc[r].w = fmaf(s.y, p1.w, acc[r].w);                         \
            acc[r].x = fmaf(s.z, p2.x, acc[r].x);                         \
            acc[r].y = fmaf(s.z, p2.y, acc[r].y);                         \
            acc[r].z = fmaf(s.z, p2.z, acc[r].z);                         \
            acc[r].w = fmaf(s.z, p2.w, acc[r].w);                         \
            acc[r].x = fmaf(s.w, p3.x, acc[r].x);                         \
            acc[r].y = fmaf(s.w, p3.y, acc[r].y);                         \
            acc[r].z = fmaf(s.w, p3.z, acc[r].z);                         \
            acc[r].w = fmaf(s.w, p3.w, acc[r].w);                         \
        }                                                                 \
    }

#define SBAR()                                                            \
    __builtin_amdgcn_sched_barrier(0);                                    \
    __builtin_amdgcn_s_barrier();                                         \
    __builtin_amdgcn_sched_barrier(0)

#define TAILSTEP(T, WAITASM)                                              \
    asm volatile(WAITASM ::: "memory");                                   \
    SBAR();                                                               \
    COMPUTE(T, (T) % 5)

__global__ __launch_bounds__(256, 4) void fused_kernel(
    const float* __restrict__ y_pred, const float* __restrict__ y_true,
    const float* __restrict__ P, const float* __restrict__ samples,
    float* __restrict__ partial /* [2*B]: per-block {logmse_i, penalty_i} */)
{
    const int tid   = threadIdx.x;
    const int wave  = tid >> 6;
    const int lane  = tid & 63;
    const int b     = blockIdx.x;
    const int r0    = wave * 5;
    const int sg    = lane >> 5;     // k-segment of the half-wave
    const int c     = lane & 31;     // column group
    const int j4    = c << 2;
    const int kbase = sg << 6;       // 0 or 64
    const int l5    = lane >> 5;     // staging: row-within-issue
    const int lx    = lane & 31;     // staging: 16B slot within row

    const float* __restrict__ Pb = P + ((size_t)b << 14);            // b*128*128
    const float* __restrict__ Sb = samples + (size_t)b * (20 * KK);  // b*20*128

    __shared__ float sP[5 * 8 * KK]; // 5-buffer ring of 8-row chunks (20KB)
    __shared__ float sS[20 * KK];    // S rows: broadcast + identity (10KB)
    __shared__ float red[4];

    // ---- stage S into LDS (global->reg->ds_write; vmcnt self-drains) ----
#pragma unroll
    for (int i = 0; i < 5; ++i) {
        const int idx = (i * 256 + tid) * 2;
        *(float2*)&sS[idx] = *(const float2*)(Sb + idx);
    }

    float4 acc[5];
#pragma unroll
    for (int r = 0; r < 5; ++r) acc[r] = make_float4(0.f, 0.f, 0.f, 0.f);

    // ---- prologue: 4 chunks in flight; own ds_writes drained ----
    STAGE(0, 0); STAGE(1, 1); STAGE(2, 2); STAGE(3, 3);
    asm volatile("s_waitcnt lgkmcnt(0)" ::: "memory");
    __builtin_amdgcn_sched_barrier(0);

    // ---- main pipeline: wait(counted) -> barrier -> compute -> prefetch ----
#pragma unroll 1
    for (int t = 0; t < 12; ++t) {
        asm volatile("s_waitcnt vmcnt(3)" ::: "memory");  // chunk t arrived
        SBAR();
        const int cb = t % 5;
        COMPUTE(t, cb);
        const int nb = (t + 4) % 5;
        STAGE(t + 4, nb);            // keep 4 chunks flying; never drain
    }
    // ---- tail: literal counted drains 3/2/1/0 ----
    TAILSTEP(12, "s_waitcnt vmcnt(3)");
    TAILSTEP(13, "s_waitcnt vmcnt(2)");
    TAILSTEP(14, "s_waitcnt vmcnt(1)");
    TAILSTEP(15, "s_waitcnt vmcnt(0)");

    // ---- combine k-halves; upper half-wave switches to identity values ----
    float w0[5], w1[5], w2[5], w3[5];
#pragma unroll
    for (int r = 0; r < 5; ++r) {
        float ax = acc[r].x + __shfl_xor(acc[r].x, 32, 64);
        float ay = acc[r].y + __shfl_xor(acc[r].y, 32, 64);
        float az = acc[r].z + __shfl_xor(acc[r].z, 32, 64);
        float aw = acc[r].w + __shfl_xor(acc[r].w, 32, 64);
        float4 idv = *(const float4*)&sS[(r0 + r) * KK + j4];
        w0[r] = fabsf(sg ? idv.x : ax);
        w1[r] = fabsf(sg ? idv.y : ay);
        w2[r] = fabsf(sg ? idv.z : az);
        w3[r] = fabsf(sg ? idv.w : aw);
    }

    // ---- m1 per row: lane max + 6-shfl butterfly (5 chains interleave) ----
    float mx[5];
#pragma unroll
    for (int r = 0; r < 5; ++r) {
        float lm = fmaxf(fmaxf(w0[r], w1[r]), fmaxf(w2[r], w3[r]));
#pragma unroll
        for (int d = 32; d >= 1; d >>= 1)
            lm = fmaxf(lm, __shfl_xor(lm, d, 64));
        mx[r] = lm;
    }

    // ---- m11 per row: LOCKSTEP ballot bisection on float bit patterns ----
    unsigned lo[5], hi[5];
#pragma unroll
    for (int r = 0; r < 5; ++r) { lo[r] = 0u; hi[r] = __float_as_uint(mx[r]); }

    while (lo[0] < hi[0] || lo[1] < hi[1] || lo[2] < hi[2] ||
           lo[3] < hi[3] || lo[4] < hi[4]) {
#pragma unroll
        for (int r = 0; r < 5; ++r) {
            unsigned mid = lo[r] + ((hi[r] - lo[r] + 1u) >> 1);
            float mf = __uint_as_float(mid);
            int cnt = __popcll(__ballot(w0[r] > mf)) + __popcll(__ballot(w1[r] > mf))
                    + __popcll(__ballot(w2[r] > mf)) + __popcll(__ballot(w3[r] > mf));
            bool g = cnt >= (MTOP + 1);
            lo[r] = g ? mid : lo[r];
            hi[r] = g ? hi[r] : mid - 1u;
        }
    }

    float hmax = 0.f;
#pragma unroll
    for (int r = 0; r < 5; ++r) {
        float m11 = __uint_as_float(lo[r] + 1u);   // exact 11th-largest
        hmax = fmaxf(hmax, mx[r] / (m11 + EPSF));  // wave-uniform
    }

    // ---- combine 4 waves; per-block partials (no atomics) ----
    if (lane == 0) red[wave] = hmax;
    __syncthreads();
    if (tid == 0) {
        float hb  = fmaxf(fmaxf(red[0], red[1]), fmaxf(red[2], red[3]));
        float ypv = y_pred[b];
        float yp  = fmaxf(ypv, EPSF);
        float yt  = fmaxf(y_true[b], EPSF);
        float d   = log2f(yt) - log2f(yp);
        partial[2 * b]     = d * d;
        partial[2 * b + 1] = fmaxf(hb - ypv, 0.f);
    }
}

__global__ __launch_bounds__(256) void finalize_kernel(
    const float* __restrict__ partial, float* __restrict__ out, float invB)
{
    const int t = threadIdx.x;
    float sl = 0.f, sp = 0.f;
#pragma unroll
    for (int i = 0; i < 8; ++i) {
        float2 v = *(const float2*)(partial + 2 * (t + i * 256));
        sl += v.x; sp += v.y;
    }
#pragma unroll
    for (int d = 32; d >= 1; d >>= 1) {
        sl += __shfl_xor(sl, d, 64);
        sp += __shfl_xor(sp, d, 64);
    }
    __shared__ float rl[4], rp[4];
    const int w = t >> 6;
    if ((t & 63) == 0) { rl[w] = sl; rp[w] = sp; }
    __syncthreads();
    if (t == 0) {
        float L = (rl[0] + rl[1] + rl[2] + rl[3]) * invB;
        float V = (rp[0] + rp[1] + rp[2] + rp[3]) * invB;
        out[0] = L + 0.5f * V;
        out[1] = L;
        out[2] = V;
    }
}

extern "C" void kernel_launch(void* const* d_in, const int* in_sizes, int n_in,
                              void* d_out, int out_size, void* d_ws, size_t ws_size,
                              hipStream_t stream) {
    const float* y_pred  = (const float*)d_in[0];
    const float* y_true  = (const float*)d_in[1];
    const float* P       = (const float*)d_in[2];
    const float* samples = (const float*)d_in[3];
    const int B = in_sizes[0];           // y_pred has B elements

    float* partial = (float*)d_ws;       // 2*B floats, fully overwritten

    fused_kernel<<<B, 256, 0, stream>>>(y_pred, y_true, P, samples, partial);
    finalize_kernel<<<1, 256, 0, stream>>>(partial, (float*)d_out, 1.0f / (float)B);
}